// Round 5
// baseline (699.108 us; speedup 1.0000x reference)
//
#include <hip/hip_runtime.h>
#include <stdint.h>

#define D_MODEL 1024
#define NHEAD   16
#define DHEAD   64
#define BATCH   4
#define SEQ     2048
#define MTOT    (BATCH*SEQ)   // 8192

typedef __attribute__((ext_vector_type(4))) float f32x4;
typedef __attribute__((ext_vector_type(8))) short bf16x8;

typedef __attribute__((address_space(3))) uint32_t lds_u32;
typedef const __attribute__((address_space(1))) uint32_t glb_u32;

__device__ static inline void gload_lds16(const void* g, void* l) {
    __builtin_amdgcn_global_load_lds((glb_u32*)g, (lds_u32*)l, 16, 0, 0);
}

__device__ static inline ushort f2bf(float f) {
    uint32_t u = __builtin_bit_cast(uint32_t, f);
    u += 0x7fffu + ((u >> 16) & 1u);   // RNE (inputs are finite)
    return (ushort)(u >> 16);
}

__device__ static inline float exp2_fast(float x) {
    float r; asm("v_exp_f32 %0, %1" : "=v"(r) : "v"(x)); return r;
}
__device__ static inline uint32_t cvt_pk_bf16(float a, float b) {
    uint32_t r;  // low half = bf16(a), high half = bf16(b)
    asm("v_cvt_pk_bf16_f32 %0, %1, %2" : "=v"(r) : "v"(a), "v"(b));
    return r;
}

// ---------------------------------------------------------------- convert
__global__ __launch_bounds__(256) void convert_kernel(
    const float4* __restrict__ x,
    const float4* __restrict__ wq, const float4* __restrict__ wk,
    const float4* __restrict__ wv, const float4* __restrict__ wo,
    ushort4* __restrict__ xb, ushort4* __restrict__ wb)
{
    const int NX4 = (MTOT * D_MODEL) / 4;
    const int NW4 = (D_MODEL * D_MODEL) / 4;
    const int TOT = NX4 + 4 * NW4;
    for (int i = blockIdx.x * blockDim.x + threadIdx.x; i < TOT;
         i += gridDim.x * blockDim.x) {
        float4 v; ushort4* dst;
        if (i < NX4) { v = x[i]; dst = &xb[i]; }
        else {
            int j = i - NX4;
            int w = j >> 18;
            int r = j & (NW4 - 1);
            const float4* s = (w == 0) ? wq : (w == 1) ? wk : (w == 2) ? wv : wo;
            v = s[r]; dst = &wb[(size_t)w * NW4 + r];
        }
        ushort4 o;
        o.x = f2bf(v.x); o.y = f2bf(v.y); o.z = f2bf(v.z); o.w = f2bf(v.w);
        *dst = o;
    }
}

// ---------------------------------------------------------------- fused QKV GEMM
// W3 = [Wq;Wk;Wv] rows 0..3071.  C[i,e] = x[i,:]·W3[e,:] + bias
__global__ __launch_bounds__(256) void gemm_qkv(
    const ushort* __restrict__ A,    // [8192,1024] bf16
    const ushort* __restrict__ W3,   // [3072,1024] bf16
    const float* __restrict__ bq, const float* __restrict__ bk,
    const float* __restrict__ bv,
    ushort* __restrict__ Qb, ushort* __restrict__ Kb, ushort* __restrict__ Vtb,
    float qscale)
{
    __shared__ __align__(16) ushort As[128 * 32];
    __shared__ __align__(16) ushort Bs[128 * 32];

    const int tid = threadIdx.x;
    const int w  = tid >> 6, l = tid & 63, lo = l & 15, hi = l >> 4;
    const int wr = w >> 1, wc = w & 1;

    const int id = blockIdx.x;                         // 0..1535
    const int mb = ((id & 7) << 3) | ((id >> 3) & 7);  // 0..63 (XCD-chunked)
    const int nb = id >> 6;                            // 0..23
    const int m0 = mb * 128, n0 = nb * 128;

    f32x4 acc[4][4] = {};
    const int srow = l >> 2;
    const int sk   = (l & 3) * 8;

    for (int kt = 0; kt < 32; ++kt) {
        const int k0 = kt * 32;
        __syncthreads();
#pragma unroll
        for (int c = 0; c < 2; ++c) {
            const int row = c * 64 + w * 16 + srow;
            gload_lds16(&A[(size_t)(m0 + row) * 1024 + k0 + sk],
                        &As[(c * 64 + w * 16) * 32]);
            gload_lds16(&W3[(size_t)(n0 + row) * 1024 + k0 + sk],
                        &Bs[(c * 64 + w * 16) * 32]);
        }
        __syncthreads();

        bf16x8 af[4], bfr[4];
#pragma unroll
        for (int mi = 0; mi < 4; ++mi)
            af[mi] = *(const bf16x8*)&As[(wr * 64 + mi * 16 + lo) * 32 + hi * 8];
#pragma unroll
        for (int ni = 0; ni < 4; ++ni)
            bfr[ni] = *(const bf16x8*)&Bs[(wc * 64 + ni * 16 + lo) * 32 + hi * 8];
#pragma unroll
        for (int mi = 0; mi < 4; ++mi)
#pragma unroll
            for (int ni = 0; ni < 4; ++ni)
                acc[mi][ni] = __builtin_amdgcn_mfma_f32_16x16x32_bf16(
                    af[mi], bfr[ni], acc[mi][ni], 0, 0, 0);
    }

    const int region = nb >> 3;         // 0:Q 1:K 2:V (block-uniform)
    const float scale = (region == 0) ? qscale : 1.0f;
    const float* bias = (region == 0) ? bq : (region == 1) ? bk : bv;
    ushort* outQK = (region == 0) ? Qb : Kb;

#pragma unroll
    for (int mi = 0; mi < 4; ++mi) {
#pragma unroll
        for (int ni = 0; ni < 4; ++ni) {
            const int gj  = n0 + wc * 64 + ni * 16 + lo;   // 0..3071
            const int lcl = gj & 1023;
            const int h = lcl >> 6, dh = lcl & 63;
            const float bj = bias[lcl];
            if (region < 2) {
#pragma unroll
                for (int r = 0; r < 4; ++r) {
                    const int gi = m0 + wr * 64 + mi * 16 + hi * 4 + r;
                    const int b = gi >> 11, s = gi & (SEQ - 1);
                    outQK[(((size_t)(b * NHEAD + h)) * SEQ + s) * DHEAD + dh] =
                        f2bf((acc[mi][ni][r] + bj) * scale);
                }
            } else {
                const int gi0 = m0 + wr * 64 + mi * 16 + hi * 4;
                const int b = gi0 >> 11, s = gi0 & (SEQ - 1);
                ushort4 o4;
                o4.x = f2bf(acc[mi][ni][0] + bj);
                o4.y = f2bf(acc[mi][ni][1] + bj);
                o4.z = f2bf(acc[mi][ni][2] + bj);
                o4.w = f2bf(acc[mi][ni][3] + bj);
                *(ushort4*)&Vtb[(((size_t)(b * NHEAD + h)) * DHEAD + dh) * SEQ + s] = o4;
            }
        }
    }
}

// ---------------------------------------------------------------- output GEMM
__global__ __launch_bounds__(256) void gemm_out(
    const ushort* __restrict__ A,
    const ushort* __restrict__ W,
    const float*  __restrict__ bias,
    float* __restrict__ out)
{
    __shared__ __align__(16) ushort As[128 * 32];
    __shared__ __align__(16) ushort Bs[128 * 32];

    const int tid = threadIdx.x;
    const int w  = tid >> 6, l = tid & 63, lo = l & 15, hi = l >> 4;
    const int wr = w >> 1, wc = w & 1;

    const int id = blockIdx.y * 8 + blockIdx.x;        // 0..511
    const int mb = ((id & 7) << 3) | ((id >> 3) & 7);
    const int nb = id >> 6;
    const int m0 = mb * 128, n0 = nb * 128;

    f32x4 acc[4][4] = {};
    const int srow = l >> 2;
    const int sk   = (l & 3) * 8;

    for (int kt = 0; kt < 32; ++kt) {
        const int k0 = kt * 32;
        __syncthreads();
#pragma unroll
        for (int c = 0; c < 2; ++c) {
            const int row = c * 64 + w * 16 + srow;
            gload_lds16(&A[(size_t)(m0 + row) * 1024 + k0 + sk],
                        &As[(c * 64 + w * 16) * 32]);
            gload_lds16(&W[(size_t)(n0 + row) * 1024 + k0 + sk],
                        &Bs[(c * 64 + w * 16) * 32]);
        }
        __syncthreads();

        bf16x8 af[4], bfr[4];
#pragma unroll
        for (int mi = 0; mi < 4; ++mi)
            af[mi] = *(const bf16x8*)&As[(wr * 64 + mi * 16 + lo) * 32 + hi * 8];
#pragma unroll
        for (int ni = 0; ni < 4; ++ni)
            bfr[ni] = *(const bf16x8*)&Bs[(wc * 64 + ni * 16 + lo) * 32 + hi * 8];
#pragma unroll
        for (int mi = 0; mi < 4; ++mi)
#pragma unroll
            for (int ni = 0; ni < 4; ++ni)
                acc[mi][ni] = __builtin_amdgcn_mfma_f32_16x16x32_bf16(
                    af[mi], bfr[ni], acc[mi][ni], 0, 0, 0);
    }

#pragma unroll
    for (int mi = 0; mi < 4; ++mi)
#pragma unroll
        for (int ni = 0; ni < 4; ++ni) {
            const int gj = n0 + wc * 64 + ni * 16 + lo;
            const float bj = bias[gj];
#pragma unroll
            for (int r = 0; r < 4; ++r) {
                const int gi = m0 + wr * 64 + mi * 16 + hi * 4 + r;
                out[(size_t)gi * D_MODEL + gj] = acc[mi][ni][r] + bj;
            }
        }
}

// ---------------------------------------------------------------- attention
// Swapped-QK^T flash attention, exp2 domain (Q pre-scaled by log2e/8).
// QBLK=128 (4 waves x 32 q-rows). Each block: one (b,h), Q-tile pair {j,15-j}
// -> uniform 34 KV-tiles/block, 512 blocks. Depth-2 K/V prefetch pipeline.
// LDS [64][64] bf16, 16B-granule XOR swizzle.
__global__ __launch_bounds__(256) void attn_kernel(
    const ushort* __restrict__ Q, const ushort* __restrict__ K,
    const ushort* __restrict__ Vt, ushort* __restrict__ ctx)
{
    __shared__ __align__(16) ushort Ks[64 * 64];
    __shared__ __align__(16) ushort Vs[64 * 64];
    __shared__ __align__(16) ushort Pq[4 * 32 * 64];

    const int tid = threadIdx.x;
    const int w = tid >> 6, l = tid & 63, lo = l & 15, hi = l >> 4;
    const int sw = lo & 7;

    const int fid = blockIdx.x;            // 0..511
    const int xcd = fid & 7;
    const int u = fid >> 3;                // 0..63
    const int g = xcd * 8 + (u & 7);       // bh; g>>3 == xcd
    const int b = g >> 4, h = g & 15;
    const int j = u >> 3;                  // 0..7 (pair index)
    const size_t base = (size_t)(b * NHEAD + h) * SEQ * DHEAD;

    const int krow = tid >> 3;             // 0..31
    const int kcol = (tid & 7) * 8;
    char* PqW = (char*)&Pq[w * 2048];

    for (int pass = 0; pass < 2; ++pass) {
        const int qt = pass ? (15 - j) : j;
        const int q0 = qt << 7;
        const int qw0 = q0 + w * 32;

        bf16x8 qf[2][2];
#pragma unroll
        for (int mi = 0; mi < 2; ++mi)
#pragma unroll
            for (int ks = 0; ks < 2; ++ks)
                qf[mi][ks] = *(const bf16x8*)&Q[base +
                    (size_t)(qw0 + mi * 16 + lo) * DHEAD + ks * 32 + hi * 8];

        f32x4 o[2][4] = {};
        float mrow[2] = {-1e30f, -1e30f}, lrow[2] = {0.f, 0.f};

        const int ntiles = (q0 + 128) >> 6;   // 2qt+2 >= 2
        bf16x8 kreg[2][2], vreg[2][2];
#pragma unroll
        for (int c = 0; c < 2; ++c) {          // prologue: tiles 0 and 1
            kreg[0][c] = *(const bf16x8*)&K[base + (size_t)(c * 32 + krow) * DHEAD + kcol];
            vreg[0][c] = *(const bf16x8*)&Vt[base + (size_t)(c * 32 + krow) * SEQ + kcol];
            kreg[1][c] = *(const bf16x8*)&K[base + (size_t)(64 + c * 32 + krow) * DHEAD + kcol];
            vreg[1][c] = *(const bf16x8*)&Vt[base + (size_t)(c * 32 + krow) * SEQ + 64 + kcol];
        }

        for (int t = 0; t < ntiles; ++t) {
            const int kv0 = t << 6;
            const int pb = t & 1;
            __syncthreads();                 // prev tile's LDS reads done
#pragma unroll
            for (int c = 0; c < 2; ++c) {    // stage K/V (swizzled)
                const int row = c * 32 + krow;
                const int g16 = (tid & 7) ^ (row & 7);
                *(bf16x8*)((char*)Ks + row * 128 + (g16 << 4)) = kreg[pb][c];
                *(bf16x8*)((char*)Vs + row * 128 + (g16 << 4)) = vreg[pb][c];
            }
            __syncthreads();
            if (t + 2 < ntiles) {            // depth-2 prefetch (T14)
                const int nv0 = kv0 + 128;
#pragma unroll
                for (int c = 0; c < 2; ++c) {
                    kreg[pb][c] = *(const bf16x8*)&K[base + (size_t)(nv0 + c * 32 + krow) * DHEAD + kcol];
                    vreg[pb][c] = *(const bf16x8*)&Vt[base + (size_t)(c * 32 + krow) * SEQ + nv0 + kcol];
                }
            }
            if (kv0 > qw0 + 31) continue;    // wave fully masked (barriers balanced)

            // ---- S^T = K Q^T  (rows=kv, cols=q=lo), log2-scaled
            f32x4 s[2][4] = {};
            __builtin_amdgcn_s_setprio(1);
#pragma unroll
            for (int ks = 0; ks < 2; ++ks) {
                bf16x8 kf[4];
#pragma unroll
                for (int nj = 0; nj < 4; ++nj)
                    kf[nj] = *(const bf16x8*)((char*)Ks + (nj * 16 + lo) * 128 +
                                              ((((ks << 2) + hi) ^ sw) << 4));
#pragma unroll
                for (int mi = 0; mi < 2; ++mi)
#pragma unroll
                    for (int nj = 0; nj < 4; ++nj)
                        s[mi][nj] = __builtin_amdgcn_mfma_f32_16x16x32_bf16(
                            kf[nj], qf[mi][ks], s[mi][nj], 0, 0, 0);
            }
            __builtin_amdgcn_s_setprio(0);

            // ---- causal mask
            if (kv0 + 63 > qw0) {
#pragma unroll
                for (int mi = 0; mi < 2; ++mi) {
                    const int gq = qw0 + mi * 16 + lo;
#pragma unroll
                    for (int nj = 0; nj < 4; ++nj)
#pragma unroll
                        for (int r = 0; r < 4; ++r) {
                            const int gk = kv0 + nj * 16 + hi * 4 + r;
                            if (gk > gq) s[mi][nj][r] = -1e30f;
                        }
                }
            }

            // ---- online softmax (q=lo lane-local), defer-max THR=8 (log2)
            float tl[2], corr[2];
#pragma unroll
            for (int mi = 0; mi < 2; ++mi) {
                float m = s[mi][0][0];
#pragma unroll
                for (int nj = 0; nj < 4; ++nj)
#pragma unroll
                    for (int r = 0; r < 4; ++r) m = fmaxf(m, s[mi][nj][r]);
                tl[mi] = m;
            }
            const bool grow = (tl[0] > mrow[0] + 8.f) | (tl[1] > mrow[1] + 8.f);
            if (__any(grow)) {
#pragma unroll
                for (int mi = 0; mi < 2; ++mi) {
                    float m2 = fmaxf(tl[mi], __shfl_xor(tl[mi], 16));
                    m2 = fmaxf(m2, __shfl_xor(m2, 32));
                    const float mn = fmaxf(mrow[mi], m2);
                    corr[mi] = exp2_fast(mrow[mi] - mn);
                    mrow[mi] = mn;
                }
#pragma unroll
                for (int mi = 0; mi < 2; ++mi)
#pragma unroll
                    for (int r = 0; r < 4; ++r) {
                        const float cb = __shfl(corr[mi], hi * 4 + r);
#pragma unroll
                        for (int ni = 0; ni < 4; ++ni) o[mi][ni][r] *= cb;
                    }
            } else { corr[0] = 1.f; corr[1] = 1.f; }

#pragma unroll
            for (int mi = 0; mi < 2; ++mi) {
                float ls = 0.f;
#pragma unroll
                for (int nj = 0; nj < 4; ++nj) {
#pragma unroll
                    for (int r = 0; r < 4; ++r) {
                        const float p = exp2_fast(s[mi][nj][r] - mrow[mi]);
                        s[mi][nj][r] = p;
                        ls += p;
                    }
                    uint2 pp;
                    pp.x = cvt_pk_bf16(s[mi][nj][0], s[mi][nj][1]);
                    pp.y = cvt_pk_bf16(s[mi][nj][2], s[mi][nj][3]);
                    const int gP = ((nj << 1) + (hi >> 1)) ^ sw;
                    *(uint2*)(PqW + (mi * 16 + lo) * 128 + (gP << 4) + ((hi & 1) << 3)) = pp;
                }
                ls += __shfl_xor(ls, 16);
                ls += __shfl_xor(ls, 32);
                lrow[mi] = lrow[mi] * corr[mi] + ls;
            }

            // ---- O += P V
            __builtin_amdgcn_s_setprio(1);
#pragma unroll
            for (int ks2 = 0; ks2 < 2; ++ks2) {
                bf16x8 pf[2], vf[4];
#pragma unroll
                for (int mi = 0; mi < 2; ++mi)
                    pf[mi] = *(const bf16x8*)(PqW + (mi * 16 + lo) * 128 +
                                              ((((ks2 << 2) + hi) ^ sw) << 4));
#pragma unroll
                for (int ni = 0; ni < 4; ++ni)
                    vf[ni] = *(const bf16x8*)((char*)Vs + (ni * 16 + lo) * 128 +
                                              ((((ks2 << 2) + hi) ^ sw) << 4));
#pragma unroll
                for (int mi = 0; mi < 2; ++mi)
#pragma unroll
                    for (int ni = 0; ni < 4; ++ni)
                        o[mi][ni] = __builtin_amdgcn_mfma_f32_16x16x32_bf16(
                            pf[mi], vf[ni], o[mi][ni], 0, 0, 0);
            }
            __builtin_amdgcn_s_setprio(0);
        }

        // ---- epilogue for this Q-tile
#pragma unroll
        for (int mi = 0; mi < 2; ++mi) {
            const float rv = 1.0f / lrow[mi];
#pragma unroll
            for (int r = 0; r < 4; ++r) {
                const float rb = __shfl(rv, hi * 4 + r);
                const int gq = qw0 + mi * 16 + hi * 4 + r;
#pragma unroll
                for (int ni = 0; ni < 4; ++ni)
                    ctx[((size_t)(b * SEQ + gq)) * D_MODEL + h * DHEAD + ni * 16 + lo] =
                        f2bf(o[mi][ni][r] * rb);
            }
        }
    }
}

// ---------------------------------------------------------------- launch
extern "C" void kernel_launch(void* const* d_in, const int* in_sizes, int n_in,
                              void* d_out, int out_size, void* d_ws, size_t ws_size,
                              hipStream_t stream) {
    const float* x  = (const float*)d_in[0];
    const float* Wq = (const float*)d_in[1];
    const float* bq = (const float*)d_in[2];
    const float* Wk = (const float*)d_in[3];
    const float* bk = (const float*)d_in[4];
    const float* Wv = (const float*)d_in[5];
    const float* bv = (const float*)d_in[6];
    const float* Wo = (const float*)d_in[7];
    const float* bo = (const float*)d_in[8];

    char* ws = (char*)d_ws;
    ushort* xb  = (ushort*)(ws);
    ushort* wb  = (ushort*)(ws + (16u << 20));
    ushort* Qb  = (ushort*)(ws + (24u << 20));
    ushort* Kb  = (ushort*)(ws + (40u << 20));
    ushort* Vtb = (ushort*)(ws + (56u << 20));
    ushort* ctx = (ushort*)(ws + (72u << 20));

    convert_kernel<<<2048, 256, 0, stream>>>(
        (const float4*)x, (const float4*)Wq, (const float4*)Wk,
        (const float4*)Wv, (const float4*)Wo, (ushort4*)xb, (ushort4*)wb);

    const int NW = D_MODEL * D_MODEL;
    const float qscale = 0.125f * 1.44269504f;   // fold log2e: softmax in exp2 domain

    gemm_qkv<<<1536, 256, 0, stream>>>(xb, wb, bq, bk, bv, Qb, Kb, Vtb, qscale);

    attn_kernel<<<512, 256, 0, stream>>>(Qb, Kb, Vtb, ctx);

    gemm_out<<<dim3(8, 64), 256, 0, stream>>>(ctx, wb + 3 * NW, bo, (float*)d_out);
}

// Round 6
// 179.268 us; speedup vs baseline: 3.8998x; 3.8998x over previous
//
#include <hip/hip_runtime.h>
#include <stdint.h>

#define D_MODEL 1024
#define NHEAD   16
#define DHEAD   64
#define BATCH   4
#define SEQ     2048
#define MTOT    (BATCH*SEQ)   // 8192

typedef __attribute__((ext_vector_type(4))) float f32x4;
typedef __attribute__((ext_vector_type(8))) short bf16x8;

typedef __attribute__((address_space(3))) uint32_t lds_u32;
typedef const __attribute__((address_space(1))) uint32_t glb_u32;

__device__ static inline void gload_lds16(const void* g, void* l) {
    __builtin_amdgcn_global_load_lds((glb_u32*)g, (lds_u32*)l, 16, 0, 0);
}

__device__ static inline ushort f2bf(float f) {
    uint32_t u = __builtin_bit_cast(uint32_t, f);
    u += 0x7fffu + ((u >> 16) & 1u);   // RNE (inputs are finite)
    return (ushort)(u >> 16);
}

__device__ static inline float exp2_fast(float x) {
    float r; asm("v_exp_f32 %0, %1" : "=v"(r) : "v"(x)); return r;
}
__device__ static inline uint32_t cvt_pk_bf16(float a, float b) {
    uint32_t r;  // low half = bf16(a), high half = bf16(b)
    asm("v_cvt_pk_bf16_f32 %0, %1, %2" : "=v"(r) : "v"(a), "v"(b));
    return r;
}

// ---------------------------------------------------------------- convert
__global__ __launch_bounds__(256) void convert_kernel(
    const float4* __restrict__ x,
    const float4* __restrict__ wq, const float4* __restrict__ wk,
    const float4* __restrict__ wv, const float4* __restrict__ wo,
    ushort4* __restrict__ xb, ushort4* __restrict__ wb)
{
    const int NX4 = (MTOT * D_MODEL) / 4;
    const int NW4 = (D_MODEL * D_MODEL) / 4;
    const int TOT = NX4 + 4 * NW4;
    for (int i = blockIdx.x * blockDim.x + threadIdx.x; i < TOT;
         i += gridDim.x * blockDim.x) {
        float4 v; ushort4* dst;
        if (i < NX4) { v = x[i]; dst = &xb[i]; }
        else {
            int j = i - NX4;
            int w = j >> 18;
            int r = j & (NW4 - 1);
            const float4* s = (w == 0) ? wq : (w == 1) ? wk : (w == 2) ? wv : wo;
            v = s[r]; dst = &wb[(size_t)w * NW4 + r];
        }
        ushort4 o;
        o.x = f2bf(v.x); o.y = f2bf(v.y); o.z = f2bf(v.z); o.w = f2bf(v.w);
        *dst = o;
    }
}

// ---------------------------------------------------------------- fused QKV GEMM
// W3 = [Wq;Wk;Wv] rows 0..3071.  C[i,e] = x[i,:]·W3[e,:] + bias
__global__ __launch_bounds__(256) void gemm_qkv(
    const ushort* __restrict__ A,    // [8192,1024] bf16
    const ushort* __restrict__ W3,   // [3072,1024] bf16
    const float* __restrict__ bq, const float* __restrict__ bk,
    const float* __restrict__ bv,
    ushort* __restrict__ Qb, ushort* __restrict__ Kb, ushort* __restrict__ Vtb,
    float qscale)
{
    __shared__ __align__(16) ushort As[128 * 32];
    __shared__ __align__(16) ushort Bs[128 * 32];

    const int tid = threadIdx.x;
    const int w  = tid >> 6, l = tid & 63, lo = l & 15, hi = l >> 4;
    const int wr = w >> 1, wc = w & 1;

    const int id = blockIdx.x;                         // 0..1535
    const int mb = ((id & 7) << 3) | ((id >> 3) & 7);  // 0..63 (XCD-chunked)
    const int nb = id >> 6;                            // 0..23
    const int m0 = mb * 128, n0 = nb * 128;

    f32x4 acc[4][4] = {};
    const int srow = l >> 2;
    const int sk   = (l & 3) * 8;

    for (int kt = 0; kt < 32; ++kt) {
        const int k0 = kt * 32;
        __syncthreads();
#pragma unroll
        for (int c = 0; c < 2; ++c) {
            const int row = c * 64 + w * 16 + srow;
            gload_lds16(&A[(size_t)(m0 + row) * 1024 + k0 + sk],
                        &As[(c * 64 + w * 16) * 32]);
            gload_lds16(&W3[(size_t)(n0 + row) * 1024 + k0 + sk],
                        &Bs[(c * 64 + w * 16) * 32]);
        }
        __syncthreads();

        bf16x8 af[4], bfr[4];
#pragma unroll
        for (int mi = 0; mi < 4; ++mi)
            af[mi] = *(const bf16x8*)&As[(wr * 64 + mi * 16 + lo) * 32 + hi * 8];
#pragma unroll
        for (int ni = 0; ni < 4; ++ni)
            bfr[ni] = *(const bf16x8*)&Bs[(wc * 64 + ni * 16 + lo) * 32 + hi * 8];
#pragma unroll
        for (int mi = 0; mi < 4; ++mi)
#pragma unroll
            for (int ni = 0; ni < 4; ++ni)
                acc[mi][ni] = __builtin_amdgcn_mfma_f32_16x16x32_bf16(
                    af[mi], bfr[ni], acc[mi][ni], 0, 0, 0);
    }

    const int region = nb >> 3;         // 0:Q 1:K 2:V (block-uniform)
    const float scale = (region == 0) ? qscale : 1.0f;
    const float* bias = (region == 0) ? bq : (region == 1) ? bk : bv;
    ushort* outQK = (region == 0) ? Qb : Kb;

#pragma unroll
    for (int mi = 0; mi < 4; ++mi) {
#pragma unroll
        for (int ni = 0; ni < 4; ++ni) {
            const int gj  = n0 + wc * 64 + ni * 16 + lo;   // 0..3071
            const int lcl = gj & 1023;
            const int h = lcl >> 6, dh = lcl & 63;
            const float bj = bias[lcl];
            if (region < 2) {
#pragma unroll
                for (int r = 0; r < 4; ++r) {
                    const int gi = m0 + wr * 64 + mi * 16 + hi * 4 + r;
                    const int b = gi >> 11, s = gi & (SEQ - 1);
                    outQK[(((size_t)(b * NHEAD + h)) * SEQ + s) * DHEAD + dh] =
                        f2bf((acc[mi][ni][r] + bj) * scale);
                }
            } else {
                const int gi0 = m0 + wr * 64 + mi * 16 + hi * 4;
                const int b = gi0 >> 11, s = gi0 & (SEQ - 1);
                ushort4 o4;
                o4.x = f2bf(acc[mi][ni][0] + bj);
                o4.y = f2bf(acc[mi][ni][1] + bj);
                o4.z = f2bf(acc[mi][ni][2] + bj);
                o4.w = f2bf(acc[mi][ni][3] + bj);
                *(ushort4*)&Vtb[(((size_t)(b * NHEAD + h)) * DHEAD + dh) * SEQ + s] = o4;
            }
        }
    }
}

// ---------------------------------------------------------------- output GEMM
__global__ __launch_bounds__(256) void gemm_out(
    const ushort* __restrict__ A,
    const ushort* __restrict__ W,
    const float*  __restrict__ bias,
    float* __restrict__ out)
{
    __shared__ __align__(16) ushort As[128 * 32];
    __shared__ __align__(16) ushort Bs[128 * 32];

    const int tid = threadIdx.x;
    const int w  = tid >> 6, l = tid & 63, lo = l & 15, hi = l >> 4;
    const int wr = w >> 1, wc = w & 1;

    const int id = blockIdx.y * 8 + blockIdx.x;        // 0..511
    const int mb = ((id & 7) << 3) | ((id >> 3) & 7);
    const int nb = id >> 6;
    const int m0 = mb * 128, n0 = nb * 128;

    f32x4 acc[4][4] = {};
    const int srow = l >> 2;
    const int sk   = (l & 3) * 8;

    for (int kt = 0; kt < 32; ++kt) {
        const int k0 = kt * 32;
        __syncthreads();
#pragma unroll
        for (int c = 0; c < 2; ++c) {
            const int row = c * 64 + w * 16 + srow;
            gload_lds16(&A[(size_t)(m0 + row) * 1024 + k0 + sk],
                        &As[(c * 64 + w * 16) * 32]);
            gload_lds16(&W[(size_t)(n0 + row) * 1024 + k0 + sk],
                        &Bs[(c * 64 + w * 16) * 32]);
        }
        __syncthreads();

        bf16x8 af[4], bfr[4];
#pragma unroll
        for (int mi = 0; mi < 4; ++mi)
            af[mi] = *(const bf16x8*)&As[(wr * 64 + mi * 16 + lo) * 32 + hi * 8];
#pragma unroll
        for (int ni = 0; ni < 4; ++ni)
            bfr[ni] = *(const bf16x8*)&Bs[(wc * 64 + ni * 16 + lo) * 32 + hi * 8];
#pragma unroll
        for (int mi = 0; mi < 4; ++mi)
#pragma unroll
            for (int ni = 0; ni < 4; ++ni)
                acc[mi][ni] = __builtin_amdgcn_mfma_f32_16x16x32_bf16(
                    af[mi], bfr[ni], acc[mi][ni], 0, 0, 0);
    }

#pragma unroll
    for (int mi = 0; mi < 4; ++mi)
#pragma unroll
        for (int ni = 0; ni < 4; ++ni) {
            const int gj = n0 + wc * 64 + ni * 16 + lo;
            const float bj = bias[gj];
#pragma unroll
            for (int r = 0; r < 4; ++r) {
                const int gi = m0 + wr * 64 + mi * 16 + hi * 4 + r;
                out[(size_t)gi * D_MODEL + gj] = acc[mi][ni][r] + bj;
            }
        }
}

// ---------------------------------------------------------------- attention
// Swapped-QK^T flash attention, exp2 domain (Q pre-scaled by log2e/8).
// QBLK=128 (4 waves x 32 q-rows). Each block: one (b,h), Q-tile pair {j,15-j}
// -> uniform 34 KV-tiles/block, 512 blocks.
// Depth-2 K/V prefetch with STATIC register buffers (rule #20: no runtime
// indexing of reg arrays) — tile loop unrolled x2 (ntiles is always even).
// LDS [64][64] bf16, 16B-granule XOR swizzle.
__global__ __launch_bounds__(256) void attn_kernel(
    const ushort* __restrict__ Q, const ushort* __restrict__ K,
    const ushort* __restrict__ Vt, ushort* __restrict__ ctx)
{
    __shared__ __align__(16) ushort Ks[64 * 64];
    __shared__ __align__(16) ushort Vs[64 * 64];
    __shared__ __align__(16) ushort Pq[4 * 32 * 64];

    const int tid = threadIdx.x;
    const int w = tid >> 6, l = tid & 63, lo = l & 15, hi = l >> 4;
    const int sw = lo & 7;

    const int fid = blockIdx.x;            // 0..511
    const int xcd = fid & 7;
    const int u = fid >> 3;                // 0..63
    const int g = xcd * 8 + (u & 7);       // bh; g>>3 == xcd
    const int b = g >> 4, h = g & 15;
    const int j = u >> 3;                  // 0..7 (pair index)
    const size_t base = (size_t)(b * NHEAD + h) * SEQ * DHEAD;

    const int krow = tid >> 3;             // 0..31
    const int kcol = (tid & 7) * 8;
    char* PqW = (char*)&Pq[w * 2048];

    for (int pass = 0; pass < 2; ++pass) {
        const int qt = pass ? (15 - j) : j;
        const int q0 = qt << 7;
        const int qw0 = q0 + w * 32;

        bf16x8 qf[2][2];
#pragma unroll
        for (int mi = 0; mi < 2; ++mi)
#pragma unroll
            for (int ks = 0; ks < 2; ++ks)
                qf[mi][ks] = *(const bf16x8*)&Q[base +
                    (size_t)(qw0 + mi * 16 + lo) * DHEAD + ks * 32 + hi * 8];

        f32x4 o[2][4] = {};
        float mrow[2] = {-1e30f, -1e30f}, lrow[2] = {0.f, 0.f};

        const int ntiles = (q0 + 128) >> 6;   // = 2*(qt+1), always even

        // Two statically-named prefetch buffers (depth-2 pipeline).
        bf16x8 kregA[2], vregA[2], kregB[2], vregB[2];
#pragma unroll
        for (int c = 0; c < 2; ++c) {          // prologue: tiles 0 and 1
            kregA[c] = *(const bf16x8*)&K[base + (size_t)(c * 32 + krow) * DHEAD + kcol];
            vregA[c] = *(const bf16x8*)&Vt[base + (size_t)(c * 32 + krow) * SEQ + kcol];
            kregB[c] = *(const bf16x8*)&K[base + (size_t)(64 + c * 32 + krow) * DHEAD + kcol];
            vregB[c] = *(const bf16x8*)&Vt[base + (size_t)(c * 32 + krow) * SEQ + 64 + kcol];
        }

        // One KV-tile: stage KR/VR -> LDS, prefetch tile t+2 into KR/VR,
        // then compute (skipped for fully-masked waves).
        auto tile_body = [&](int t, bf16x8 (&KR)[2], bf16x8 (&VR)[2]) {
            const int kv0 = t << 6;
            __syncthreads();                 // prev tile's LDS reads done
#pragma unroll
            for (int c = 0; c < 2; ++c) {    // stage K/V (swizzled)
                const int row = c * 32 + krow;
                const int g16 = (tid & 7) ^ (row & 7);
                *(bf16x8*)((char*)Ks + row * 128 + (g16 << 4)) = KR[c];
                *(bf16x8*)((char*)Vs + row * 128 + (g16 << 4)) = VR[c];
            }
            __syncthreads();
            if (t + 2 < ntiles) {            // depth-2 prefetch (T14)
                const int nv0 = kv0 + 128;
#pragma unroll
                for (int c = 0; c < 2; ++c) {
                    KR[c] = *(const bf16x8*)&K[base + (size_t)(nv0 + c * 32 + krow) * DHEAD + kcol];
                    VR[c] = *(const bf16x8*)&Vt[base + (size_t)(c * 32 + krow) * SEQ + nv0 + kcol];
                }
            }
            if (kv0 > qw0 + 31) return;      // wave fully masked (barriers balanced)

            // ---- S^T = K Q^T  (rows=kv, cols=q=lo), log2-scaled
            f32x4 s[2][4] = {};
            __builtin_amdgcn_s_setprio(1);
#pragma unroll
            for (int ks = 0; ks < 2; ++ks) {
                bf16x8 kf[4];
#pragma unroll
                for (int nj = 0; nj < 4; ++nj)
                    kf[nj] = *(const bf16x8*)((char*)Ks + (nj * 16 + lo) * 128 +
                                              ((((ks << 2) + hi) ^ sw) << 4));
#pragma unroll
                for (int mi = 0; mi < 2; ++mi)
#pragma unroll
                    for (int nj = 0; nj < 4; ++nj)
                        s[mi][nj] = __builtin_amdgcn_mfma_f32_16x16x32_bf16(
                            kf[nj], qf[mi][ks], s[mi][nj], 0, 0, 0);
            }
            __builtin_amdgcn_s_setprio(0);

            // ---- causal mask
            if (kv0 + 63 > qw0) {
#pragma unroll
                for (int mi = 0; mi < 2; ++mi) {
                    const int gq = qw0 + mi * 16 + lo;
#pragma unroll
                    for (int nj = 0; nj < 4; ++nj)
#pragma unroll
                        for (int r = 0; r < 4; ++r) {
                            const int gk = kv0 + nj * 16 + hi * 4 + r;
                            if (gk > gq) s[mi][nj][r] = -1e30f;
                        }
                }
            }

            // ---- online softmax (q=lo lane-local), defer-max THR=8 (log2)
            float tl[2], corr[2];
#pragma unroll
            for (int mi = 0; mi < 2; ++mi) {
                float m = s[mi][0][0];
#pragma unroll
                for (int nj = 0; nj < 4; ++nj)
#pragma unroll
                    for (int r = 0; r < 4; ++r) m = fmaxf(m, s[mi][nj][r]);
                tl[mi] = m;
            }
            const bool grow = (tl[0] > mrow[0] + 8.f) | (tl[1] > mrow[1] + 8.f);
            if (__any(grow)) {
#pragma unroll
                for (int mi = 0; mi < 2; ++mi) {
                    float m2 = fmaxf(tl[mi], __shfl_xor(tl[mi], 16));
                    m2 = fmaxf(m2, __shfl_xor(m2, 32));
                    const float mn = fmaxf(mrow[mi], m2);
                    corr[mi] = exp2_fast(mrow[mi] - mn);
                    mrow[mi] = mn;
                }
#pragma unroll
                for (int mi = 0; mi < 2; ++mi)
#pragma unroll
                    for (int r = 0; r < 4; ++r) {
                        const float cb = __shfl(corr[mi], hi * 4 + r);
#pragma unroll
                        for (int ni = 0; ni < 4; ++ni) o[mi][ni][r] *= cb;
                    }
            } else { corr[0] = 1.f; corr[1] = 1.f; }

#pragma unroll
            for (int mi = 0; mi < 2; ++mi) {
                float ls = 0.f;
#pragma unroll
                for (int nj = 0; nj < 4; ++nj) {
#pragma unroll
                    for (int r = 0; r < 4; ++r) {
                        const float p = exp2_fast(s[mi][nj][r] - mrow[mi]);
                        s[mi][nj][r] = p;
                        ls += p;
                    }
                    uint2 pp;
                    pp.x = cvt_pk_bf16(s[mi][nj][0], s[mi][nj][1]);
                    pp.y = cvt_pk_bf16(s[mi][nj][2], s[mi][nj][3]);
                    const int gP = ((nj << 1) + (hi >> 1)) ^ sw;
                    *(uint2*)(PqW + (mi * 16 + lo) * 128 + (gP << 4) + ((hi & 1) << 3)) = pp;
                }
                ls += __shfl_xor(ls, 16);
                ls += __shfl_xor(ls, 32);
                lrow[mi] = lrow[mi] * corr[mi] + ls;
            }

            // ---- O += P V
            __builtin_amdgcn_s_setprio(1);
#pragma unroll
            for (int ks2 = 0; ks2 < 2; ++ks2) {
                bf16x8 pf[2], vf[4];
#pragma unroll
                for (int mi = 0; mi < 2; ++mi)
                    pf[mi] = *(const bf16x8*)(PqW + (mi * 16 + lo) * 128 +
                                              ((((ks2 << 2) + hi) ^ sw) << 4));
#pragma unroll
                for (int ni = 0; ni < 4; ++ni)
                    vf[ni] = *(const bf16x8*)((char*)Vs + (ni * 16 + lo) * 128 +
                                              ((((ks2 << 2) + hi) ^ sw) << 4));
#pragma unroll
                for (int mi = 0; mi < 2; ++mi)
#pragma unroll
                    for (int ni = 0; ni < 4; ++ni)
                        o[mi][ni] = __builtin_amdgcn_mfma_f32_16x16x32_bf16(
                            pf[mi], vf[ni], o[mi][ni], 0, 0, 0);
            }
            __builtin_amdgcn_s_setprio(0);
        };

        for (int tt = 0; tt < ntiles; tt += 2) {
            tile_body(tt,     kregA, vregA);   // even tile: buffer A
            tile_body(tt + 1, kregB, vregB);   // odd tile:  buffer B
        }

        // ---- epilogue for this Q-tile
#pragma unroll
        for (int mi = 0; mi < 2; ++mi) {
            const float rv = 1.0f / lrow[mi];
#pragma unroll
            for (int r = 0; r < 4; ++r) {
                const float rb = __shfl(rv, hi * 4 + r);
                const int gq = qw0 + mi * 16 + hi * 4 + r;
#pragma unroll
                for (int ni = 0; ni < 4; ++ni)
                    ctx[((size_t)(b * SEQ + gq)) * D_MODEL + h * DHEAD + ni * 16 + lo] =
                        f2bf(o[mi][ni][r] * rb);
            }
        }
    }
}

// ---------------------------------------------------------------- launch
extern "C" void kernel_launch(void* const* d_in, const int* in_sizes, int n_in,
                              void* d_out, int out_size, void* d_ws, size_t ws_size,
                              hipStream_t stream) {
    const float* x  = (const float*)d_in[0];
    const float* Wq = (const float*)d_in[1];
    const float* bq = (const float*)d_in[2];
    const float* Wk = (const float*)d_in[3];
    const float* bk = (const float*)d_in[4];
    const float* Wv = (const float*)d_in[5];
    const float* bv = (const float*)d_in[6];
    const float* Wo = (const float*)d_in[7];
    const float* bo = (const float*)d_in[8];

    char* ws = (char*)d_ws;
    ushort* xb  = (ushort*)(ws);
    ushort* wb  = (ushort*)(ws + (16u << 20));
    ushort* Qb  = (ushort*)(ws + (24u << 20));
    ushort* Kb  = (ushort*)(ws + (40u << 20));
    ushort* Vtb = (ushort*)(ws + (56u << 20));
    ushort* ctx = (ushort*)(ws + (72u << 20));

    convert_kernel<<<2048, 256, 0, stream>>>(
        (const float4*)x, (const float4*)Wq, (const float4*)Wk,
        (const float4*)Wv, (const float4*)Wo, (ushort4*)xb, (ushort4*)wb);

    const int NW = D_MODEL * D_MODEL;
    const float qscale = 0.125f * 1.44269504f;   // fold log2e: softmax in exp2 domain

    gemm_qkv<<<1536, 256, 0, stream>>>(xb, wb, bq, bk, bv, Qb, Kb, Vtb, qscale);

    attn_kernel<<<512, 256, 0, stream>>>(Qb, Kb, Vtb, ctx);

    gemm_out<<<dim3(8, 64), 256, 0, stream>>>(ctx, wb + 3 * NW, bo, (float*)d_out);
}

// Round 7
// 171.395 us; speedup vs baseline: 4.0789x; 1.0459x over previous
//
#include <hip/hip_runtime.h>
#include <stdint.h>

#define D_MODEL 1024
#define NHEAD   16
#define DHEAD   64
#define BATCH   4
#define SEQ     2048
#define MTOT    (BATCH*SEQ)   // 8192

typedef __attribute__((ext_vector_type(4))) float f32x4;
typedef __attribute__((ext_vector_type(8))) short bf16x8;

typedef __attribute__((address_space(3))) uint32_t lds_u32;
typedef const __attribute__((address_space(1))) uint32_t glb_u32;

__device__ static inline void gload_lds16(const void* g, void* l) {
    __builtin_amdgcn_global_load_lds((glb_u32*)g, (lds_u32*)l, 16, 0, 0);
}

__device__ static inline ushort f2bf(float f) {
    uint32_t u = __builtin_bit_cast(uint32_t, f);
    u += 0x7fffu + ((u >> 16) & 1u);   // RNE (inputs are finite)
    return (ushort)(u >> 16);
}

__device__ static inline float exp2_fast(float x) {
    float r; asm("v_exp_f32 %0, %1" : "=v"(r) : "v"(x)); return r;
}
__device__ static inline uint32_t cvt_pk_bf16(float a, float b) {
    uint32_t r;  // low half = bf16(a), high half = bf16(b)
    asm("v_cvt_pk_bf16_f32 %0, %1, %2" : "=v"(r) : "v"(a), "v"(b));
    return r;
}

// ---------------------------------------------------------------- convert
__global__ __launch_bounds__(256) void convert_kernel(
    const float4* __restrict__ x,
    const float4* __restrict__ wq, const float4* __restrict__ wk,
    const float4* __restrict__ wv, const float4* __restrict__ wo,
    ushort4* __restrict__ xb, ushort4* __restrict__ wb)
{
    const int NX4 = (MTOT * D_MODEL) / 4;
    const int NW4 = (D_MODEL * D_MODEL) / 4;
    const int TOT = NX4 + 4 * NW4;
    for (int i = blockIdx.x * blockDim.x + threadIdx.x; i < TOT;
         i += gridDim.x * blockDim.x) {
        float4 v; ushort4* dst;
        if (i < NX4) { v = x[i]; dst = &xb[i]; }
        else {
            int j = i - NX4;
            int w = j >> 18;
            int r = j & (NW4 - 1);
            const float4* s = (w == 0) ? wq : (w == 1) ? wk : (w == 2) ? wv : wo;
            v = s[r]; dst = &wb[(size_t)w * NW4 + r];
        }
        ushort4 o;
        o.x = f2bf(v.x); o.y = f2bf(v.y); o.z = f2bf(v.z); o.w = f2bf(v.w);
        *dst = o;
    }
}

// =================================================================
// Pipelined 128x128 GEMM core (BK=32): 4-stage LDS ring, counted
// vmcnt (AITER pattern: never 0 in steady state), raw s_barrier,
// granule-XOR LDS swizzle (pre-swizzled global source, rule #21).
// Per iter: issue stage(t+3) -> ds_read frags(t) -> lgkmcnt(0) ->
// 16 MFMA -> vmcnt(8) -> s_barrier.
// =================================================================

// swizzle of 16B granule index within a 64B row
#define GSWZ(r) ((((r) >> 2) ^ (r)) & 3)

#define GEMM_PIPE_BODY(APTR, BPTR)                                          \
    __shared__ __align__(16) ushort S[4 * 2 * 4096]; /* [st][A|B][128*32] */\
    const int tid = threadIdx.x;                                            \
    const int w = tid >> 6, l = tid & 63, lo = l & 15, hi = l >> 4;         \
    const int wr = w >> 1, wc = w & 1;                                      \
    const int srow = l >> 2, gg = l & 3;                                    \
    const int r0 = w * 16 + srow, r1 = 64 + w * 16 + srow;                  \
    const int q0 = gg ^ GSWZ(r0), q1 = gg ^ GSWZ(r1);                       \
    const ushort* aS0 = (APTR) + (size_t)(m0 + r0) * 1024 + q0 * 8;         \
    const ushort* aS1 = (APTR) + (size_t)(m0 + r1) * 1024 + q1 * 8;         \
    const ushort* bS0 = (BPTR) + (size_t)(n0 + r0) * 1024 + q0 * 8;         \
    const ushort* bS1 = (BPTR) + (size_t)(n0 + r1) * 1024 + q1 * 8;         \
    const int ldsA0 = (w * 16) * 32, ldsA1 = (64 + w * 16) * 32;            \
    int offA[4], offB[4];                                                   \
    _Pragma("unroll")                                                       \
    for (int mi = 0; mi < 4; ++mi) {                                        \
        const int rA = wr * 64 + mi * 16 + lo;                              \
        offA[mi] = rA * 64 + ((hi ^ GSWZ(rA)) << 4);                        \
        const int rB = wc * 64 + mi * 16 + lo;                              \
        offB[mi] = rB * 64 + ((hi ^ GSWZ(rB)) << 4);                        \
    }                                                                       \
    f32x4 acc[4][4] = {};                                                   \
    auto stage = [&](int st, int t) {                                       \
        ushort* b = &S[st * 8192];                                          \
        const int ko = t * 32;                                              \
        gload_lds16(aS0 + ko, b + ldsA0);                                   \
        gload_lds16(aS1 + ko, b + ldsA1);                                   \
        gload_lds16(bS0 + ko, b + 4096 + ldsA0);                            \
        gload_lds16(bS1 + ko, b + 4096 + ldsA1);                            \
    };                                                                      \
    stage(0, 0); stage(1, 1); stage(2, 2);                                  \
    asm volatile("s_waitcnt vmcnt(8)" ::: "memory");                        \
    __builtin_amdgcn_s_barrier();                                           \
    __builtin_amdgcn_sched_barrier(0);                                      \
    int st = 0;                                                             \
    for (int t = 0; t < 32; ++t) {                                          \
        if (t + 3 < 32) stage((st + 3) & 3, t + 3);                         \
        const char* base = (const char*)&S[st * 8192];                      \
        bf16x8 af[4], bfr[4];                                               \
        _Pragma("unroll")                                                   \
        for (int mi = 0; mi < 4; ++mi) {                                    \
            af[mi]  = *(const bf16x8*)(base + offA[mi]);                    \
            bfr[mi] = *(const bf16x8*)(base + 8192 + offB[mi]);             \
        }                                                                   \
        asm volatile("s_waitcnt lgkmcnt(0)" ::: "memory");                  \
        __builtin_amdgcn_sched_barrier(0);                                  \
        __builtin_amdgcn_s_setprio(1);                                      \
        _Pragma("unroll")                                                   \
        for (int mi = 0; mi < 4; ++mi)                                      \
            _Pragma("unroll")                                               \
            for (int ni = 0; ni < 4; ++ni)                                  \
                acc[mi][ni] = __builtin_amdgcn_mfma_f32_16x16x32_bf16(      \
                    af[mi], bfr[ni], acc[mi][ni], 0, 0, 0);                 \
        __builtin_amdgcn_s_setprio(0);                                      \
        if (t + 3 < 32)      { asm volatile("s_waitcnt vmcnt(8)" ::: "memory"); } \
        else if (t == 29)    { asm volatile("s_waitcnt vmcnt(4)" ::: "memory"); } \
        else if (t == 30)    { asm volatile("s_waitcnt vmcnt(0)" ::: "memory"); } \
        __builtin_amdgcn_s_barrier();                                       \
        __builtin_amdgcn_sched_barrier(0);                                  \
        st = (st + 1) & 3;                                                  \
    }

// ---------------------------------------------------------------- fused QKV GEMM
// W3 = [Wq;Wk;Wv] rows 0..3071.  C[i,e] = x[i,:]·W3[e,:] + bias
__global__ __launch_bounds__(256) void gemm_qkv(
    const ushort* __restrict__ A,    // [8192,1024] bf16
    const ushort* __restrict__ W3,   // [3072,1024] bf16
    const float* __restrict__ bq, const float* __restrict__ bk,
    const float* __restrict__ bv,
    ushort* __restrict__ Qb, ushort* __restrict__ Kb, ushort* __restrict__ Vtb,
    float qscale)
{
    const int id = blockIdx.x;                         // 0..1535
    const int mb = ((id & 7) << 3) | ((id >> 3) & 7);  // 0..63 (XCD-chunked)
    const int nb = id >> 6;                            // 0..23
    const int m0 = mb * 128, n0 = nb * 128;

    GEMM_PIPE_BODY(A, W3)

    const int region = nb >> 3;         // 0:Q 1:K 2:V (block-uniform)
    const float scale = (region == 0) ? qscale : 1.0f;
    const float* bias = (region == 0) ? bq : (region == 1) ? bk : bv;
    ushort* outQK = (region == 0) ? Qb : Kb;

#pragma unroll
    for (int mi = 0; mi < 4; ++mi) {
#pragma unroll
        for (int ni = 0; ni < 4; ++ni) {
            const int gj  = n0 + wc * 64 + ni * 16 + lo;   // 0..3071
            const int lcl = gj & 1023;
            const int h = lcl >> 6, dh = lcl & 63;
            const float bj = bias[lcl];
            if (region < 2) {
#pragma unroll
                for (int r = 0; r < 4; ++r) {
                    const int gi = m0 + wr * 64 + mi * 16 + hi * 4 + r;
                    const int b = gi >> 11, s = gi & (SEQ - 1);
                    outQK[(((size_t)(b * NHEAD + h)) * SEQ + s) * DHEAD + dh] =
                        f2bf((acc[mi][ni][r] + bj) * scale);
                }
            } else {
                const int gi0 = m0 + wr * 64 + mi * 16 + hi * 4;
                const int b = gi0 >> 11, s = gi0 & (SEQ - 1);
                ushort4 o4;
                o4.x = f2bf(acc[mi][ni][0] + bj);
                o4.y = f2bf(acc[mi][ni][1] + bj);
                o4.z = f2bf(acc[mi][ni][2] + bj);
                o4.w = f2bf(acc[mi][ni][3] + bj);
                *(ushort4*)&Vtb[(((size_t)(b * NHEAD + h)) * DHEAD + dh) * SEQ + s] = o4;
            }
        }
    }
}

// ---------------------------------------------------------------- output GEMM
__global__ __launch_bounds__(256) void gemm_out(
    const ushort* __restrict__ A,
    const ushort* __restrict__ W,
    const float*  __restrict__ bias,
    float* __restrict__ out)
{
    const int id = blockIdx.x;                         // 0..511
    const int mb = ((id & 7) << 3) | ((id >> 3) & 7);
    const int nb = id >> 6;                            // 0..7
    const int m0 = mb * 128, n0 = nb * 128;

    GEMM_PIPE_BODY(A, W)

#pragma unroll
    for (int mi = 0; mi < 4; ++mi)
#pragma unroll
        for (int ni = 0; ni < 4; ++ni) {
            const int gj = n0 + wc * 64 + ni * 16 + lo;
            const float bj = bias[gj];
#pragma unroll
            for (int r = 0; r < 4; ++r) {
                const int gi = m0 + wr * 64 + mi * 16 + hi * 4 + r;
                out[(size_t)gi * D_MODEL + gj] = acc[mi][ni][r] + bj;
            }
        }
}

// ---------------------------------------------------------------- attention
// Swapped-QK^T flash attention, exp2 domain (Q pre-scaled by log2e/8).
// QBLK=128 (4 waves x 32 q-rows). Each block: one (b,h), Q-tile pair {j,15-j}
// -> uniform 34 KV-tiles/block, 512 blocks.
// Depth-2 K/V prefetch with STATIC register buffers (rule #20).
// LDS [64][64] bf16, 16B-granule XOR swizzle.
__global__ __launch_bounds__(256) void attn_kernel(
    const ushort* __restrict__ Q, const ushort* __restrict__ K,
    const ushort* __restrict__ Vt, ushort* __restrict__ ctx)
{
    __shared__ __align__(16) ushort Ks[64 * 64];
    __shared__ __align__(16) ushort Vs[64 * 64];
    __shared__ __align__(16) ushort Pq[4 * 32 * 64];

    const int tid = threadIdx.x;
    const int w = tid >> 6, l = tid & 63, lo = l & 15, hi = l >> 4;
    const int sw = lo & 7;

    const int fid = blockIdx.x;            // 0..511
    const int xcd = fid & 7;
    const int u = fid >> 3;                // 0..63
    const int g = xcd * 8 + (u & 7);       // bh; g>>3 == xcd
    const int b = g >> 4, h = g & 15;
    const int j = u >> 3;                  // 0..7 (pair index)
    const size_t base = (size_t)(b * NHEAD + h) * SEQ * DHEAD;

    const int krow = tid >> 3;             // 0..31
    const int kcol = (tid & 7) * 8;
    char* PqW = (char*)&Pq[w * 2048];

    for (int pass = 0; pass < 2; ++pass) {
        const int qt = pass ? (15 - j) : j;
        const int q0 = qt << 7;
        const int qw0 = q0 + w * 32;

        bf16x8 qf[2][2];
#pragma unroll
        for (int mi = 0; mi < 2; ++mi)
#pragma unroll
            for (int ks = 0; ks < 2; ++ks)
                qf[mi][ks] = *(const bf16x8*)&Q[base +
                    (size_t)(qw0 + mi * 16 + lo) * DHEAD + ks * 32 + hi * 8];

        f32x4 o[2][4] = {};
        float mrow[2] = {-1e30f, -1e30f}, lrow[2] = {0.f, 0.f};

        const int ntiles = (q0 + 128) >> 6;   // = 2*(qt+1), always even

        bf16x8 kregA[2], vregA[2], kregB[2], vregB[2];
#pragma unroll
        for (int c = 0; c < 2; ++c) {          // prologue: tiles 0 and 1
            kregA[c] = *(const bf16x8*)&K[base + (size_t)(c * 32 + krow) * DHEAD + kcol];
            vregA[c] = *(const bf16x8*)&Vt[base + (size_t)(c * 32 + krow) * SEQ + kcol];
            kregB[c] = *(const bf16x8*)&K[base + (size_t)(64 + c * 32 + krow) * DHEAD + kcol];
            vregB[c] = *(const bf16x8*)&Vt[base + (size_t)(c * 32 + krow) * SEQ + 64 + kcol];
        }

        auto tile_body = [&](int t, bf16x8 (&KR)[2], bf16x8 (&VR)[2]) {
            const int kv0 = t << 6;
            __syncthreads();                 // prev tile's LDS reads done
#pragma unroll
            for (int c = 0; c < 2; ++c) {    // stage K/V (swizzled)
                const int row = c * 32 + krow;
                const int g16 = (tid & 7) ^ (row & 7);
                *(bf16x8*)((char*)Ks + row * 128 + (g16 << 4)) = KR[c];
                *(bf16x8*)((char*)Vs + row * 128 + (g16 << 4)) = VR[c];
            }
            __syncthreads();
            if (t + 2 < ntiles) {            // depth-2 prefetch (T14)
                const int nv0 = kv0 + 128;
#pragma unroll
                for (int c = 0; c < 2; ++c) {
                    KR[c] = *(const bf16x8*)&K[base + (size_t)(nv0 + c * 32 + krow) * DHEAD + kcol];
                    VR[c] = *(const bf16x8*)&Vt[base + (size_t)(c * 32 + krow) * SEQ + nv0 + kcol];
                }
            }
            if (kv0 > qw0 + 31) return;      // wave fully masked (barriers balanced)

            // ---- S^T = K Q^T  (rows=kv, cols=q=lo), log2-scaled
            f32x4 s[2][4] = {};
            __builtin_amdgcn_s_setprio(1);
#pragma unroll
            for (int ks = 0; ks < 2; ++ks) {
                bf16x8 kf[4];
#pragma unroll
                for (int nj = 0; nj < 4; ++nj)
                    kf[nj] = *(const bf16x8*)((char*)Ks + (nj * 16 + lo) * 128 +
                                              ((((ks << 2) + hi) ^ sw) << 4));
#pragma unroll
                for (int mi = 0; mi < 2; ++mi)
#pragma unroll
                    for (int nj = 0; nj < 4; ++nj)
                        s[mi][nj] = __builtin_amdgcn_mfma_f32_16x16x32_bf16(
                            kf[nj], qf[mi][ks], s[mi][nj], 0, 0, 0);
            }
            __builtin_amdgcn_s_setprio(0);

            // ---- causal mask
            if (kv0 + 63 > qw0) {
#pragma unroll
                for (int mi = 0; mi < 2; ++mi) {
                    const int gq = qw0 + mi * 16 + lo;
#pragma unroll
                    for (int nj = 0; nj < 4; ++nj)
#pragma unroll
                        for (int r = 0; r < 4; ++r) {
                            const int gk = kv0 + nj * 16 + hi * 4 + r;
                            if (gk > gq) s[mi][nj][r] = -1e30f;
                        }
                }
            }

            // ---- online softmax (q=lo lane-local), defer-max THR=8 (log2)
            float tl[2], corr[2];
#pragma unroll
            for (int mi = 0; mi < 2; ++mi) {
                float m = s[mi][0][0];
#pragma unroll
                for (int nj = 0; nj < 4; ++nj)
#pragma unroll
                    for (int r = 0; r < 4; ++r) m = fmaxf(m, s[mi][nj][r]);
                tl[mi] = m;
            }
            const bool grow = (tl[0] > mrow[0] + 8.f) | (tl[1] > mrow[1] + 8.f);
            if (__any(grow)) {
#pragma unroll
                for (int mi = 0; mi < 2; ++mi) {
                    float m2 = fmaxf(tl[mi], __shfl_xor(tl[mi], 16));
                    m2 = fmaxf(m2, __shfl_xor(m2, 32));
                    const float mn = fmaxf(mrow[mi], m2);
                    corr[mi] = exp2_fast(mrow[mi] - mn);
                    mrow[mi] = mn;
                }
#pragma unroll
                for (int mi = 0; mi < 2; ++mi)
#pragma unroll
                    for (int r = 0; r < 4; ++r) {
                        const float cb = __shfl(corr[mi], hi * 4 + r);
#pragma unroll
                        for (int ni = 0; ni < 4; ++ni) o[mi][ni][r] *= cb;
                    }
            } else { corr[0] = 1.f; corr[1] = 1.f; }

#pragma unroll
            for (int mi = 0; mi < 2; ++mi) {
                float ls = 0.f;
#pragma unroll
                for (int nj = 0; nj < 4; ++nj) {
#pragma unroll
                    for (int r = 0; r < 4; ++r) {
                        const float p = exp2_fast(s[mi][nj][r] - mrow[mi]);
                        s[mi][nj][r] = p;
                        ls += p;
                    }
                    uint2 pp;
                    pp.x = cvt_pk_bf16(s[mi][nj][0], s[mi][nj][1]);
                    pp.y = cvt_pk_bf16(s[mi][nj][2], s[mi][nj][3]);
                    const int gP = ((nj << 1) + (hi >> 1)) ^ sw;
                    *(uint2*)(PqW + (mi * 16 + lo) * 128 + (gP << 4) + ((hi & 1) << 3)) = pp;
                }
                ls += __shfl_xor(ls, 16);
                ls += __shfl_xor(ls, 32);
                lrow[mi] = lrow[mi] * corr[mi] + ls;
            }

            // ---- O += P V
            __builtin_amdgcn_s_setprio(1);
#pragma unroll
            for (int ks2 = 0; ks2 < 2; ++ks2) {
                bf16x8 pf[2], vf[4];
#pragma unroll
                for (int mi = 0; mi < 2; ++mi)
                    pf[mi] = *(const bf16x8*)(PqW + (mi * 16 + lo) * 128 +
                                              ((((ks2 << 2) + hi) ^ sw) << 4));
#pragma unroll
                for (int ni = 0; ni < 4; ++ni)
                    vf[ni] = *(const bf16x8*)((char*)Vs + (ni * 16 + lo) * 128 +
                                              ((((ks2 << 2) + hi) ^ sw) << 4));
#pragma unroll
                for (int mi = 0; mi < 2; ++mi)
#pragma unroll
                    for (int ni = 0; ni < 4; ++ni)
                        o[mi][ni] = __builtin_amdgcn_mfma_f32_16x16x32_bf16(
                            pf[mi], vf[ni], o[mi][ni], 0, 0, 0);
            }
            __builtin_amdgcn_s_setprio(0);
        };

        for (int tt = 0; tt < ntiles; tt += 2) {
            tile_body(tt,     kregA, vregA);   // even tile: buffer A
            tile_body(tt + 1, kregB, vregB);   // odd tile:  buffer B
        }

        // ---- epilogue for this Q-tile
#pragma unroll
        for (int mi = 0; mi < 2; ++mi) {
            const float rv = 1.0f / lrow[mi];
#pragma unroll
            for (int r = 0; r < 4; ++r) {
                const float rb = __shfl(rv, hi * 4 + r);
                const int gq = qw0 + mi * 16 + hi * 4 + r;
#pragma unroll
                for (int ni = 0; ni < 4; ++ni)
                    ctx[((size_t)(b * SEQ + gq)) * D_MODEL + h * DHEAD + ni * 16 + lo] =
                        f2bf(o[mi][ni][r] * rb);
            }
        }
    }
}

// ---------------------------------------------------------------- launch
extern "C" void kernel_launch(void* const* d_in, const int* in_sizes, int n_in,
                              void* d_out, int out_size, void* d_ws, size_t ws_size,
                              hipStream_t stream) {
    const float* x  = (const float*)d_in[0];
    const float* Wq = (const float*)d_in[1];
    const float* bq = (const float*)d_in[2];
    const float* Wk = (const float*)d_in[3];
    const float* bk = (const float*)d_in[4];
    const float* Wv = (const float*)d_in[5];
    const float* bv = (const float*)d_in[6];
    const float* Wo = (const float*)d_in[7];
    const float* bo = (const float*)d_in[8];

    char* ws = (char*)d_ws;
    ushort* xb  = (ushort*)(ws);
    ushort* wb  = (ushort*)(ws + (16u << 20));
    ushort* Qb  = (ushort*)(ws + (24u << 20));
    ushort* Kb  = (ushort*)(ws + (40u << 20));
    ushort* Vtb = (ushort*)(ws + (56u << 20));
    ushort* ctx = (ushort*)(ws + (72u << 20));

    convert_kernel<<<2048, 256, 0, stream>>>(
        (const float4*)x, (const float4*)Wq, (const float4*)Wk,
        (const float4*)Wv, (const float4*)Wo, (ushort4*)xb, (ushort4*)wb);

    const int NW = D_MODEL * D_MODEL;
    const float qscale = 0.125f * 1.44269504f;   // fold log2e: softmax in exp2 domain

    gemm_qkv<<<1536, 256, 0, stream>>>(xb, wb, bq, bk, bv, Qb, Kb, Vtb, qscale);

    attn_kernel<<<512, 256, 0, stream>>>(Qb, Kb, Vtb, ctx);

    gemm_out<<<512, 256, 0, stream>>>(ctx, wb + 3 * NW, bo, (float*)d_out);
}

// Round 8
// 170.484 us; speedup vs baseline: 4.1007x; 1.0053x over previous
//
#include <hip/hip_runtime.h>
#include <stdint.h>

#define D_MODEL 1024
#define NHEAD   16
#define DHEAD   64
#define BATCH   4
#define SEQ     2048
#define MTOT    (BATCH*SEQ)   // 8192

typedef __attribute__((ext_vector_type(4)))  float f32x4;
typedef __attribute__((ext_vector_type(16))) float f32x16;
typedef __attribute__((ext_vector_type(8)))  short bf16x8;

typedef __attribute__((address_space(3))) uint32_t lds_u32;
typedef const __attribute__((address_space(1))) uint32_t glb_u32;

__device__ static inline void gload_lds16(const void* g, void* l) {
    __builtin_amdgcn_global_load_lds((glb_u32*)g, (lds_u32*)l, 16, 0, 0);
}

__device__ static inline ushort f2bf(float f) {
    uint32_t u = __builtin_bit_cast(uint32_t, f);
    u += 0x7fffu + ((u >> 16) & 1u);   // RNE (inputs are finite)
    return (ushort)(u >> 16);
}

__device__ static inline float exp2_fast(float x) {
    float r; asm("v_exp_f32 %0, %1" : "=v"(r) : "v"(x)); return r;
}
__device__ static inline uint32_t cvt_pk_bf16(float a, float b) {
    uint32_t r;  // low half = bf16(a), high half = bf16(b)
    asm("v_cvt_pk_bf16_f32 %0, %1, %2" : "=v"(r) : "v"(a), "v"(b));
    return r;
}

// ---------------------------------------------------------------- convert
__global__ __launch_bounds__(256) void convert_kernel(
    const float4* __restrict__ x,
    const float4* __restrict__ wq, const float4* __restrict__ wk,
    const float4* __restrict__ wv, const float4* __restrict__ wo,
    ushort4* __restrict__ xb, ushort4* __restrict__ wb)
{
    const int NX4 = (MTOT * D_MODEL) / 4;
    const int NW4 = (D_MODEL * D_MODEL) / 4;
    const int TOT = NX4 + 4 * NW4;
    for (int i = blockIdx.x * blockDim.x + threadIdx.x; i < TOT;
         i += gridDim.x * blockDim.x) {
        float4 v; ushort4* dst;
        if (i < NX4) { v = x[i]; dst = &xb[i]; }
        else {
            int j = i - NX4;
            int w = j >> 18;
            int r = j & (NW4 - 1);
            const float4* s = (w == 0) ? wq : (w == 1) ? wk : (w == 2) ? wv : wo;
            v = s[r]; dst = &wb[(size_t)w * NW4 + r];
        }
        ushort4 o;
        o.x = f2bf(v.x); o.y = f2bf(v.y); o.z = f2bf(v.z); o.w = f2bf(v.w);
        *dst = o;
    }
}

// =================================================================
// Pipelined 128x128 GEMM core (BK=32), 32x32x16 MFMA (2x FLOP per
// LDS byte vs 16x16x32). 3-stage LDS ring (48KB -> 3 blocks/CU),
// counted vmcnt(4) (loads in flight across barriers; drain only in
// tail), raw s_barrier, granule-XOR swizzle with pre-swizzled global
// source (rule #21).
// Wave (wr,wc) owns 64x64 output = 2x2 subtiles of 32x32.
// A/B frag: row(col)=lane&31, k=(lane>>5)*8+e (bf16x8 = b128 read).
// C/D: col=lane&31, row=(reg&3)+8*(reg>>2)+4*(lane>>5).
// =================================================================

// swizzle of 16B granule index within a 64B row
#define GSWZ(r) ((((r) >> 2) ^ (r)) & 3)

#define GEMM_PIPE_BODY(APTR, BPTR)                                          \
    __shared__ __align__(16) ushort S[3 * 2 * 4096]; /* [st][A|B][128*32] */\
    const int tid = threadIdx.x;                                            \
    const int w = tid >> 6, l = tid & 63;                                   \
    const int lo32 = l & 31, hi2 = l >> 5;                                  \
    const int wr = w >> 1, wc = w & 1;                                      \
    const int srow = l >> 2, gg = l & 3;                                    \
    const int r0 = w * 16 + srow, r1 = 64 + w * 16 + srow;                  \
    const int sq0 = gg ^ GSWZ(r0), sq1 = gg ^ GSWZ(r1);                     \
    const ushort* aS0 = (APTR) + (size_t)(m0 + r0) * 1024 + sq0 * 8;        \
    const ushort* aS1 = (APTR) + (size_t)(m0 + r1) * 1024 + sq1 * 8;        \
    const ushort* bS0 = (BPTR) + (size_t)(n0 + r0) * 1024 + sq0 * 8;        \
    const ushort* bS1 = (BPTR) + (size_t)(n0 + r1) * 1024 + sq1 * 8;        \
    const int ldsA0 = (w * 16) * 32, ldsA1 = (64 + w * 16) * 32;            \
    int offA[2][2], offB[2][2];                                             \
    _Pragma("unroll")                                                       \
    for (int mi = 0; mi < 2; ++mi)                                          \
        _Pragma("unroll")                                                   \
        for (int ks = 0; ks < 2; ++ks) {                                    \
            const int rA = wr * 64 + mi * 32 + lo32;                        \
            offA[mi][ks] = rA * 64 + (((ks * 2 + hi2) ^ GSWZ(rA)) << 4);    \
            const int rB = wc * 64 + mi * 32 + lo32;                        \
            offB[mi][ks] = rB * 64 + (((ks * 2 + hi2) ^ GSWZ(rB)) << 4);    \
        }                                                                   \
    f32x16 acc[2][2] = {};                                                  \
    auto stage = [&](int st_, int t_) {                                     \
        ushort* bp = &S[st_ * 8192];                                        \
        const int ko = t_ * 32;                                             \
        gload_lds16(aS0 + ko, bp + ldsA0);                                  \
        gload_lds16(aS1 + ko, bp + ldsA1);                                  \
        gload_lds16(bS0 + ko, bp + 4096 + ldsA0);                           \
        gload_lds16(bS1 + ko, bp + 4096 + ldsA1);                           \
    };                                                                      \
    stage(0, 0); stage(1, 1);                                               \
    asm volatile("s_waitcnt vmcnt(4)" ::: "memory");                        \
    __builtin_amdgcn_s_barrier();                                           \
    __builtin_amdgcn_sched_barrier(0);                                      \
    int st = 0;                                                             \
    for (int t = 0; t < 32; ++t) {                                          \
        if (t + 2 < 32) {                                                   \
            int sn = st + 2; if (sn >= 3) sn -= 3;                          \
            stage(sn, t + 2);                                               \
        }                                                                   \
        const char* base = (const char*)&S[st * 8192];                      \
        bf16x8 af[2][2], bf[2][2];                                          \
        _Pragma("unroll")                                                   \
        for (int mi = 0; mi < 2; ++mi)                                      \
            _Pragma("unroll")                                               \
            for (int ks = 0; ks < 2; ++ks) {                                \
                af[mi][ks] = *(const bf16x8*)(base + offA[mi][ks]);         \
                bf[mi][ks] = *(const bf16x8*)(base + 8192 + offB[mi][ks]);  \
            }                                                               \
        asm volatile("s_waitcnt lgkmcnt(0)" ::: "memory");                  \
        __builtin_amdgcn_sched_barrier(0);                                  \
        __builtin_amdgcn_s_setprio(1);                                      \
        _Pragma("unroll")                                                   \
        for (int ks = 0; ks < 2; ++ks)                                      \
            _Pragma("unroll")                                               \
            for (int mi = 0; mi < 2; ++mi)                                  \
                _Pragma("unroll")                                           \
                for (int ni = 0; ni < 2; ++ni)                              \
                    acc[mi][ni] = __builtin_amdgcn_mfma_f32_32x32x16_bf16(  \
                        af[mi][ks], bf[ni][ks], acc[mi][ni], 0, 0, 0);      \
        __builtin_amdgcn_s_setprio(0);                                      \
        if (t + 2 < 32)   { asm volatile("s_waitcnt vmcnt(4)" ::: "memory"); } \
        else if (t == 30) { asm volatile("s_waitcnt vmcnt(0)" ::: "memory"); } \
        if (t < 31) {                                                       \
            __builtin_amdgcn_s_barrier();                                   \
            __builtin_amdgcn_sched_barrier(0);                              \
        }                                                                   \
        ++st; if (st >= 3) st = 0;                                          \
    }

// ---------------------------------------------------------------- fused QKV GEMM
// W3 = [Wq;Wk;Wv] rows 0..3071.  C[i,e] = x[i,:]·W3[e,:] + bias
__global__ __launch_bounds__(256) void gemm_qkv(
    const ushort* __restrict__ A,    // [8192,1024] bf16
    const ushort* __restrict__ W3,   // [3072,1024] bf16
    const float* __restrict__ bq, const float* __restrict__ bk,
    const float* __restrict__ bv,
    ushort* __restrict__ Qb, ushort* __restrict__ Kb, ushort* __restrict__ Vtb,
    float qscale)
{
    const int id = blockIdx.x;                         // 0..1535
    const int mb = ((id & 7) << 3) | ((id >> 3) & 7);  // 0..63 (XCD-chunked)
    const int nb = id >> 6;                            // 0..23
    const int m0 = mb * 128, n0 = nb * 128;

    GEMM_PIPE_BODY(A, W3)

    const int region = nb >> 3;         // 0:Q 1:K 2:V (block-uniform)
    const float scale = (region == 0) ? qscale : 1.0f;
    const float* bias = (region == 0) ? bq : (region == 1) ? bk : bv;
    ushort* outQK = (region == 0) ? Qb : Kb;

#pragma unroll
    for (int mi = 0; mi < 2; ++mi) {
#pragma unroll
        for (int ni = 0; ni < 2; ++ni) {
            const int gj  = n0 + wc * 64 + ni * 32 + lo32;   // 0..3071
            const int lcl = gj & 1023;
            const int h = lcl >> 6, dh = lcl & 63;
            const float bj = bias[lcl];
#pragma unroll
            for (int rq = 0; rq < 4; ++rq) {
                const int gi0 = m0 + wr * 64 + mi * 32 + 8 * rq + 4 * hi2;
                const int b = gi0 >> 11, s0 = gi0 & (SEQ - 1);
                if (region < 2) {
#pragma unroll
                    for (int rr = 0; rr < 4; ++rr)
                        outQK[(((size_t)(b * NHEAD + h)) * SEQ + s0 + rr) * DHEAD + dh] =
                            f2bf((acc[mi][ni][rq * 4 + rr] + bj) * scale);
                } else {
                    ushort4 o4;
                    o4.x = f2bf(acc[mi][ni][rq * 4 + 0] + bj);
                    o4.y = f2bf(acc[mi][ni][rq * 4 + 1] + bj);
                    o4.z = f2bf(acc[mi][ni][rq * 4 + 2] + bj);
                    o4.w = f2bf(acc[mi][ni][rq * 4 + 3] + bj);
                    *(ushort4*)&Vtb[(((size_t)(b * NHEAD + h)) * DHEAD + dh) * SEQ + s0] = o4;
                }
            }
        }
    }
}

// ---------------------------------------------------------------- output GEMM
__global__ __launch_bounds__(256) void gemm_out(
    const ushort* __restrict__ A,
    const ushort* __restrict__ W,
    const float*  __restrict__ bias,
    float* __restrict__ out)
{
    const int id = blockIdx.x;                         // 0..511
    const int mb = ((id & 7) << 3) | ((id >> 3) & 7);
    const int nb = id >> 6;                            // 0..7
    const int m0 = mb * 128, n0 = nb * 128;

    GEMM_PIPE_BODY(A, W)

#pragma unroll
    for (int mi = 0; mi < 2; ++mi)
#pragma unroll
        for (int ni = 0; ni < 2; ++ni) {
            const int gj = n0 + wc * 64 + ni * 32 + lo32;
            const float bj = bias[gj];
#pragma unroll
            for (int rq = 0; rq < 4; ++rq) {
                const int gi0 = m0 + wr * 64 + mi * 32 + 8 * rq + 4 * hi2;
#pragma unroll
                for (int rr = 0; rr < 4; ++rr)
                    out[(size_t)(gi0 + rr) * D_MODEL + gj] =
                        acc[mi][ni][rq * 4 + rr] + bj;
            }
        }
}

// ---------------------------------------------------------------- attention
// Swapped-QK^T flash attention, exp2 domain (Q pre-scaled by log2e/8).
// QBLK=128 (4 waves x 32 q-rows). Each block: one (b,h), Q-tile pair {j,15-j}
// -> uniform 34 KV-tiles/block, 512 blocks.
// Depth-2 K/V prefetch with STATIC register buffers (rule #20).
// LDS [64][64] bf16, 16B-granule XOR swizzle.
__global__ __launch_bounds__(256) void attn_kernel(
    const ushort* __restrict__ Q, const ushort* __restrict__ K,
    const ushort* __restrict__ Vt, ushort* __restrict__ ctx)
{
    __shared__ __align__(16) ushort Ks[64 * 64];
    __shared__ __align__(16) ushort Vs[64 * 64];
    __shared__ __align__(16) ushort Pq[4 * 32 * 64];

    const int tid = threadIdx.x;
    const int w = tid >> 6, l = tid & 63, lo = l & 15, hi = l >> 4;
    const int sw = lo & 7;

    const int fid = blockIdx.x;            // 0..511
    const int xcd = fid & 7;
    const int u = fid >> 3;                // 0..63
    const int g = xcd * 8 + (u & 7);       // bh; g>>3 == xcd
    const int b = g >> 4, h = g & 15;
    const int j = u >> 3;                  // 0..7 (pair index)
    const size_t base = (size_t)(b * NHEAD + h) * SEQ * DHEAD;

    const int krow = tid >> 3;             // 0..31
    const int kcol = (tid & 7) * 8;
    char* PqW = (char*)&Pq[w * 2048];

    for (int pass = 0; pass < 2; ++pass) {
        const int qt = pass ? (15 - j) : j;
        const int q0 = qt << 7;
        const int qw0 = q0 + w * 32;

        bf16x8 qf[2][2];
#pragma unroll
        for (int mi = 0; mi < 2; ++mi)
#pragma unroll
            for (int ks = 0; ks < 2; ++ks)
                qf[mi][ks] = *(const bf16x8*)&Q[base +
                    (size_t)(qw0 + mi * 16 + lo) * DHEAD + ks * 32 + hi * 8];

        f32x4 o[2][4] = {};
        float mrow[2] = {-1e30f, -1e30f}, lrow[2] = {0.f, 0.f};

        const int ntiles = (q0 + 128) >> 6;   // = 2*(qt+1), always even

        bf16x8 kregA[2], vregA[2], kregB[2], vregB[2];
#pragma unroll
        for (int c = 0; c < 2; ++c) {          // prologue: tiles 0 and 1
            kregA[c] = *(const bf16x8*)&K[base + (size_t)(c * 32 + krow) * DHEAD + kcol];
            vregA[c] = *(const bf16x8*)&Vt[base + (size_t)(c * 32 + krow) * SEQ + kcol];
            kregB[c] = *(const bf16x8*)&K[base + (size_t)(64 + c * 32 + krow) * DHEAD + kcol];
            vregB[c] = *(const bf16x8*)&Vt[base + (size_t)(c * 32 + krow) * SEQ + 64 + kcol];
        }

        auto tile_body = [&](int t, bf16x8 (&KR)[2], bf16x8 (&VR)[2]) {
            const int kv0 = t << 6;
            __syncthreads();                 // prev tile's LDS reads done
#pragma unroll
            for (int c = 0; c < 2; ++c) {    // stage K/V (swizzled)
                const int row = c * 32 + krow;
                const int g16 = (tid & 7) ^ (row & 7);
                *(bf16x8*)((char*)Ks + row * 128 + (g16 << 4)) = KR[c];
                *(bf16x8*)((char*)Vs + row * 128 + (g16 << 4)) = VR[c];
            }
            __syncthreads();
            if (t + 2 < ntiles) {            // depth-2 prefetch (T14)
                const int nv0 = kv0 + 128;
#pragma unroll
                for (int c = 0; c < 2; ++c) {
                    KR[c] = *(const bf16x8*)&K[base + (size_t)(nv0 + c * 32 + krow) * DHEAD + kcol];
                    VR[c] = *(const bf16x8*)&Vt[base + (size_t)(c * 32 + krow) * SEQ + nv0 + kcol];
                }
            }
            if (kv0 > qw0 + 31) return;      // wave fully masked (barriers balanced)

            // ---- S^T = K Q^T  (rows=kv, cols=q=lo), log2-scaled
            f32x4 s[2][4] = {};
            __builtin_amdgcn_s_setprio(1);
#pragma unroll
            for (int ks = 0; ks < 2; ++ks) {
                bf16x8 kf[4];
#pragma unroll
                for (int nj = 0; nj < 4; ++nj)
                    kf[nj] = *(const bf16x8*)((char*)Ks + (nj * 16 + lo) * 128 +
                                              ((((ks << 2) + hi) ^ sw) << 4));
#pragma unroll
                for (int mi = 0; mi < 2; ++mi)
#pragma unroll
                    for (int nj = 0; nj < 4; ++nj)
                        s[mi][nj] = __builtin_amdgcn_mfma_f32_16x16x32_bf16(
                            kf[nj], qf[mi][ks], s[mi][nj], 0, 0, 0);
            }
            __builtin_amdgcn_s_setprio(0);

            // ---- causal mask
            if (kv0 + 63 > qw0) {
#pragma unroll
                for (int mi = 0; mi < 2; ++mi) {
                    const int gq = qw0 + mi * 16 + lo;
#pragma unroll
                    for (int nj = 0; nj < 4; ++nj)
#pragma unroll
                        for (int r = 0; r < 4; ++r) {
                            const int gk = kv0 + nj * 16 + hi * 4 + r;
                            if (gk > gq) s[mi][nj][r] = -1e30f;
                        }
                }
            }

            // ---- online softmax (q=lo lane-local), defer-max THR=8 (log2)
            float tl[2], corr[2];
#pragma unroll
            for (int mi = 0; mi < 2; ++mi) {
                float m = s[mi][0][0];
#pragma unroll
                for (int nj = 0; nj < 4; ++nj)
#pragma unroll
                    for (int r = 0; r < 4; ++r) m = fmaxf(m, s[mi][nj][r]);
                tl[mi] = m;
            }
            const bool grow = (tl[0] > mrow[0] + 8.f) | (tl[1] > mrow[1] + 8.f);
            if (__any(grow)) {
#pragma unroll
                for (int mi = 0; mi < 2; ++mi) {
                    float m2 = fmaxf(tl[mi], __shfl_xor(tl[mi], 16));
                    m2 = fmaxf(m2, __shfl_xor(m2, 32));
                    const float mn = fmaxf(mrow[mi], m2);
                    corr[mi] = exp2_fast(mrow[mi] - mn);
                    mrow[mi] = mn;
                }
#pragma unroll
                for (int mi = 0; mi < 2; ++mi)
#pragma unroll
                    for (int r = 0; r < 4; ++r) {
                        const float cb = __shfl(corr[mi], hi * 4 + r);
#pragma unroll
                        for (int ni = 0; ni < 4; ++ni) o[mi][ni][r] *= cb;
                    }
            } else { corr[0] = 1.f; corr[1] = 1.f; }

#pragma unroll
            for (int mi = 0; mi < 2; ++mi) {
                float ls = 0.f;
#pragma unroll
                for (int nj = 0; nj < 4; ++nj) {
#pragma unroll
                    for (int r = 0; r < 4; ++r) {
                        const float p = exp2_fast(s[mi][nj][r] - mrow[mi]);
                        s[mi][nj][r] = p;
                        ls += p;
                    }
                    uint2 pp;
                    pp.x = cvt_pk_bf16(s[mi][nj][0], s[mi][nj][1]);
                    pp.y = cvt_pk_bf16(s[mi][nj][2], s[mi][nj][3]);
                    const int gP = ((nj << 1) + (hi >> 1)) ^ sw;
                    *(uint2*)(PqW + (mi * 16 + lo) * 128 + (gP << 4) + ((hi & 1) << 3)) = pp;
                }
                ls += __shfl_xor(ls, 16);
                ls += __shfl_xor(ls, 32);
                lrow[mi] = lrow[mi] * corr[mi] + ls;
            }

            // ---- O += P V
            __builtin_amdgcn_s_setprio(1);
#pragma unroll
            for (int ks2 = 0; ks2 < 2; ++ks2) {
                bf16x8 pf[2], vf[4];
#pragma unroll
                for (int mi = 0; mi < 2; ++mi)
                    pf[mi] = *(const bf16x8*)(PqW + (mi * 16 + lo) * 128 +
                                              ((((ks2 << 2) + hi) ^ sw) << 4));
#pragma unroll
                for (int ni = 0; ni < 4; ++ni)
                    vf[ni] = *(const bf16x8*)((char*)Vs + (ni * 16 + lo) * 128 +
                                              ((((ks2 << 2) + hi) ^ sw) << 4));
#pragma unroll
                for (int mi = 0; mi < 2; ++mi)
#pragma unroll
                    for (int ni = 0; ni < 4; ++ni)
                        o[mi][ni] = __builtin_amdgcn_mfma_f32_16x16x32_bf16(
                            pf[mi], vf[ni], o[mi][ni], 0, 0, 0);
            }
            __builtin_amdgcn_s_setprio(0);
        };

        for (int tt = 0; tt < ntiles; tt += 2) {
            tile_body(tt,     kregA, vregA);   // even tile: buffer A
            tile_body(tt + 1, kregB, vregB);   // odd tile:  buffer B
        }

        // ---- epilogue for this Q-tile
#pragma unroll
        for (int mi = 0; mi < 2; ++mi) {
            const float rv = 1.0f / lrow[mi];
#pragma unroll
            for (int r = 0; r < 4; ++r) {
                const float rb = __shfl(rv, hi * 4 + r);
                const int gq = qw0 + mi * 16 + hi * 4 + r;
#pragma unroll
                for (int ni = 0; ni < 4; ++ni)
                    ctx[((size_t)(b * SEQ + gq)) * D_MODEL + h * DHEAD + ni * 16 + lo] =
                        f2bf(o[mi][ni][r] * rb);
            }
        }
    }
}

// ---------------------------------------------------------------- launch
extern "C" void kernel_launch(void* const* d_in, const int* in_sizes, int n_in,
                              void* d_out, int out_size, void* d_ws, size_t ws_size,
                              hipStream_t stream) {
    const float* x  = (const float*)d_in[0];
    const float* Wq = (const float*)d_in[1];
    const float* bq = (const float*)d_in[2];
    const float* Wk = (const float*)d_in[3];
    const float* bk = (const float*)d_in[4];
    const float* Wv = (const float*)d_in[5];
    const float* bv = (const float*)d_in[6];
    const float* Wo = (const float*)d_in[7];
    const float* bo = (const float*)d_in[8];

    char* ws = (char*)d_ws;
    ushort* xb  = (ushort*)(ws);
    ushort* wb  = (ushort*)(ws + (16u << 20));
    ushort* Qb  = (ushort*)(ws + (24u << 20));
    ushort* Kb  = (ushort*)(ws + (40u << 20));
    ushort* Vtb = (ushort*)(ws + (56u << 20));
    ushort* ctx = (ushort*)(ws + (72u << 20));

    convert_kernel<<<2048, 256, 0, stream>>>(
        (const float4*)x, (const float4*)Wq, (const float4*)Wk,
        (const float4*)Wv, (const float4*)Wo, (ushort4*)xb, (ushort4*)wb);

    const int NW = D_MODEL * D_MODEL;
    const float qscale = 0.125f * 1.44269504f;   // fold log2e: softmax in exp2 domain

    gemm_qkv<<<1536, 256, 0, stream>>>(xb, wb, bq, bk, bv, Qb, Kb, Vtb, qscale);

    attn_kernel<<<512, 256, 0, stream>>>(Qb, Kb, Vtb, ctx);

    gemm_out<<<512, 256, 0, stream>>>(ctx, wb + 3 * NW, bo, (float*)d_out);
}